// Round 3
// baseline (25.640 us; speedup 1.0000x reference)
//
#include <hip/hip_runtime.h>

#define NBATCH 32
#define LPATH 256
#define NSEG 255          // L-1 segments
#define SIGLEN 4680       // 8 + 64 + 512 + 4096
#define PSTRIDE 4736      // padded partial stride in floats (16B-aligned)
#define INV6 (1.0f/6.0f)
#define INV24 (1.0f/24.0f)

// Exchange buffer for one wave's full signature (conflict-free layouts, see R2).
struct __align__(16) CBuf {
    float T4t[64 * 64];   // [ (c*8+e)*64 + lane ]
    float T3b[8 * 68];    // [ x*68 + y*8 + z ], padded stride 68
    float T2[64];
    float T1[8];
};

// ---- general Chen product helpers (lane l=(a<<3)|b owns S2[ab],S3[ab*],S4[ab**]) ----
__device__ __forceinline__ void publish_sig(CBuf& B, const float S4[64],
                                            const float S3[8], float S2, float a1a,
                                            int l, int a, int b) {
    #pragma unroll
    for (int c = 0; c < 8; ++c)
        #pragma unroll
        for (int e = 0; e < 8; ++e)
            B.T4t[(c * 8 + e) * 64 + l] = S4[c * 8 + e];
    #pragma unroll
    for (int c = 0; c < 8; ++c)
        B.T3b[a * 68 + b * 8 + c] = S3[c];
    B.T2[l] = S2;
    if (b == 0) B.T1[a] = a1a;
}

__device__ __forceinline__ void absorb_sig(const CBuf& B, float S4[64], float S3[8],
                                           float& S2, float& a1a, int l, int a, int b) {
    const float4 t1lo = *(const float4*)&B.T1[0];
    const float4 t1hi = *(const float4*)&B.T1[4];
    const float t1r[8] = {t1lo.x, t1lo.y, t1lo.z, t1lo.w,
                          t1hi.x, t1hi.y, t1hi.z, t1hi.w};
    const float t1a = B.T1[a];
    const float t1b = B.T1[b];
    // R4[abce] = A4 + A3[abc] T1[e] + A2[ab] T2[ce] + A1[a] T3[bce] + T4
    #pragma unroll
    for (int c = 0; c < 8; ++c) {
        const float4 t2lo = *(const float4*)&B.T2[c * 8];
        const float4 t2hi = *(const float4*)&B.T2[c * 8 + 4];
        const float t2r[8] = {t2lo.x, t2lo.y, t2lo.z, t2lo.w,
                              t2hi.x, t2hi.y, t2hi.z, t2hi.w};
        const float4 t3lo = *(const float4*)&B.T3b[b * 68 + c * 8];
        const float4 t3hi = *(const float4*)&B.T3b[b * 68 + c * 8 + 4];
        const float t3r[8] = {t3lo.x, t3lo.y, t3lo.z, t3lo.w,
                              t3hi.x, t3hi.y, t3hi.z, t3hi.w};
        #pragma unroll
        for (int e = 0; e < 8; ++e)
            S4[c * 8 + e] += S3[c] * t1r[e] + S2 * t2r[e]
                           + a1a * t3r[e] + B.T4t[(c * 8 + e) * 64 + l];
    }
    // R3[abc] = A3 + A2[ab] T1[c] + A1[a] T2[bc] + T3[abc]
    #pragma unroll
    for (int c = 0; c < 8; ++c)
        S3[c] += S2 * t1r[c] + a1a * B.T2[b * 8 + c] + B.T3b[a * 68 + b * 8 + c];
    S2 += a1a * t1b + B.T2[l];
    a1a += t1a;
}

// 3-round binary tree over 8 waves; wave 0 ends with the block's combined signature.
__device__ __forceinline__ void tree3(CBuf* bufs, float S4[64], float S3[8],
                                      float& S2, float& a1a, int w, int l, int a, int b) {
    #pragma unroll
    for (int r = 0; r < 3; ++r) {
        const int stride = 1 << r;
        const int m = (stride << 1) - 1;
        if ((w & m) == stride)
            publish_sig(bufs[w >> (r + 1)], S4, S3, S2, a1a, l, a, b);
        __syncthreads();
        if ((w & m) == 0)
            absorb_sig(bufs[w >> (r + 1)], S4, S3, S2, a1a, l, a, b);
        __syncthreads();
    }
}

// ---------- kernel 1: 256 blocks = 32 batches x 8 chunks of 32 segments ----------
__global__ __launch_bounds__(512) void sig_chunk_kernel(const float* __restrict__ path,
                                                        float* __restrict__ ws) {
    const int blk = blockIdx.x;
    const int n  = blk >> 3;
    const int cb = blk & 7;
    const int t = threadIdx.x;
    const int w = t >> 6, l = t & 63, a = l >> 3, b = l & 7;

    __shared__ float dbuf[32 * 8];
    __shared__ CBuf bufs[4];

    // increments for this block's 32 segments (segment 255 padded to d=0 == identity)
    const float* prow = path + n * (LPATH * 8) + cb * 256;
    for (int i = t; i < 32 * 8; i += 512) {
        const int seg = cb * 32 + (i >> 3);
        dbuf[i] = (seg < NSEG) ? (prow[i + 8] - prow[i]) : 0.f;
    }
    __syncthreads();

    float S4[64], S3[8], S2 = 0.f, a1a = 0.f;
    #pragma unroll
    for (int j = 0; j < 64; ++j) S4[j] = 0.f;
    #pragma unroll
    for (int c = 0; c < 8; ++c) S3[c] = 0.f;

    // scan 4 segments, fully unrolled
    #pragma unroll
    for (int ss = 0; ss < 4; ++ss) {
        const int s = w * 4 + ss;
        const float4 dlo = *(const float4*)&dbuf[s * 8];
        const float4 dhi = *(const float4*)&dbuf[s * 8 + 4];
        const float dr[8] = {dlo.x, dlo.y, dlo.z, dlo.w, dhi.x, dhi.y, dhi.z, dhi.w};
        const float da = dbuf[s * 8 + a];
        const float db = dbuf[s * 8 + b];
        const float dab = da * db;
        const float P = dab * INV24 + a1a * db * INV6 + S2 * 0.5f;
        const float Q = dab * INV6  + a1a * db * 0.5f + S2;
        float K[8];
        #pragma unroll
        for (int c = 0; c < 8; ++c) K[c] = dr[c] * P + S3[c];
        #pragma unroll
        for (int c = 0; c < 8; ++c)
            #pragma unroll
            for (int e = 0; e < 8; ++e)
                S4[c * 8 + e] += dr[e] * K[c];
        #pragma unroll
        for (int c = 0; c < 8; ++c) S3[c] += dr[c] * Q;
        S2 += db * (da * 0.5f + a1a);
        a1a += da;
    }

    tree3(bufs, S4, S3, S2, a1a, w, l, a, b);

    // wave 0 stores the partial signature (same layout as final output)
    if (w == 0) {
        float* o = ws + blk * PSTRIDE;
        if (b == 0) o[a] = a1a;
        o[8 + l] = S2;
        *(float4*)&o[72 + l * 8]     = make_float4(S3[0], S3[1], S3[2], S3[3]);
        *(float4*)&o[72 + l * 8 + 4] = make_float4(S3[4], S3[5], S3[6], S3[7]);
        #pragma unroll
        for (int q = 0; q < 16; ++q)
            *(float4*)&o[584 + l * 64 + q * 4] =
                make_float4(S4[q * 4], S4[q * 4 + 1], S4[q * 4 + 2], S4[q * 4 + 3]);
    }
}

// ---------- kernel 2: 32 blocks; wave w loads partial (n,w), 3-round tree ----------
__global__ __launch_bounds__(512) void sig_combine_kernel(const float* __restrict__ ws,
                                                          float* __restrict__ out) {
    const int n = blockIdx.x;
    const int t = threadIdx.x;
    const int w = t >> 6, l = t & 63, a = l >> 3, b = l & 7;

    __shared__ CBuf bufs[4];

    const float* p = ws + (n * 8 + w) * PSTRIDE;
    float S4[64], S3[8], S2, a1a;
    #pragma unroll
    for (int q = 0; q < 16; ++q) {
        const float4 v = *(const float4*)&p[584 + l * 64 + q * 4];
        S4[q * 4] = v.x; S4[q * 4 + 1] = v.y; S4[q * 4 + 2] = v.z; S4[q * 4 + 3] = v.w;
    }
    {
        const float4 v0 = *(const float4*)&p[72 + l * 8];
        const float4 v1 = *(const float4*)&p[72 + l * 8 + 4];
        S3[0] = v0.x; S3[1] = v0.y; S3[2] = v0.z; S3[3] = v0.w;
        S3[4] = v1.x; S3[5] = v1.y; S3[6] = v1.z; S3[7] = v1.w;
    }
    S2 = p[8 + l];
    a1a = p[a];

    tree3(bufs, S4, S3, S2, a1a, w, l, a, b);

    if (w == 0) {
        float* o = out + n * SIGLEN;
        if (b == 0) o[a] = a1a;
        o[8 + l] = S2;
        *(float4*)&o[72 + l * 8]     = make_float4(S3[0], S3[1], S3[2], S3[3]);
        *(float4*)&o[72 + l * 8 + 4] = make_float4(S3[4], S3[5], S3[6], S3[7]);
        #pragma unroll
        for (int q = 0; q < 16; ++q)
            *(float4*)&o[584 + l * 64 + q * 4] =
                make_float4(S4[q * 4], S4[q * 4 + 1], S4[q * 4 + 2], S4[q * 4 + 3]);
    }
}

extern "C" void kernel_launch(void* const* d_in, const int* in_sizes, int n_in,
                              void* d_out, int out_size, void* d_ws, size_t ws_size,
                              hipStream_t stream) {
    const float* path = (const float*)d_in[0];
    float* ws = (float*)d_ws;
    float* out = (float*)d_out;
    sig_chunk_kernel<<<NBATCH * 8, 512, 0, stream>>>(path, ws);
    sig_combine_kernel<<<NBATCH, 512, 0, stream>>>(ws, out);
}